// Round 20
// baseline (3311.149 us; speedup 1.0000x reference)
//
#include <hip/hip_runtime.h>
#include <hip/hip_fp16.h>

#define F_IN 1433
#define BCAP 96        // bucket capacity; deg ~ Poisson(32), P(>96) ~ 1e-18
#define WSTR 2048      // wt row stride in halfs (global, L2-resident)
#define SREP 6         // scatter reps (rep 0 = real, 1..5 = scratch regions)

// edge_index int32: src = ei[0:E], dst = ei[E:2E]
// MEASUREMENT ROUND #2: scatter rep'd into disjoint zeroed regions; aggs rep'd
// with zoff trick (R15). True cost = dispatch_dur / rep. gemm known (169).

typedef _Float16 f16x8 __attribute__((ext_vector_type(8)));
typedef float    f32x4 __attribute__((ext_vector_type(4)));

// zero SREP*N cnt words + build fp16 W^T table
__global__ __launch_bounds__(256) void k_prep(const float* __restrict__ W1,
    int* __restrict__ cnt, _Float16* __restrict__ wt, int N)
{
    int i = blockIdx.x * 256 + threadIdx.x;
    if (i < SREP * N) cnt[i] = 0;
    if (i < 16 * WSTR) {
        int c = i >> 11, k = i & (WSTR - 1);
        float v = (k < F_IN) ? W1[k * 16 + c] : 0.0f;
        wt[i] = (_Float16)v;
    }
}

// histogram + bucket scatter; rep r>0 targets disjoint scratch regions
__global__ __launch_bounds__(256) void k_scatter(const int* __restrict__ ei,
    int* cnt, int* bucket, int E, int N, int rep)
{
    int e = blockIdx.x * 256 + threadIdx.x;
    if (e >= E) return;
    int s = ei[e], d = ei[E + e];
    if ((unsigned)s >= (unsigned)N || (unsigned)d >= (unsigned)N) return;
    for (int r = 0; r < rep; ++r) {
        int* C = cnt + (size_t)r * N;
        int* B = bucket + (size_t)r * N * BCAP;
        int slot = atomicAdd(&C[d], 1);
        if (slot < BCAP) B[(size_t)d * BCAP + slot] = s;
    }
}

// ---------------- layer-1 GEMM via MFMA (R12 verbatim) ----------------
__global__ __launch_bounds__(256, 4) void k_gemm(
    const float* __restrict__ x, const _Float16* __restrict__ wt,
    const int* __restrict__ cnt, float* __restrict__ s, int N)
{
    int tid = threadIdx.x;
    int wv = tid >> 6, lane = tid & 63;
    int ntiles = (N + 15) >> 4;
    int tile = blockIdx.x * 4 + wv;
    if (tile >= ntiles) return;

    int rc = lane & 15;          // A-row within tile, and B/D column
    int g  = lane >> 4;          // k-group
    int row = tile * 16 + rc;
    const float* xr = x + (size_t)((row < N) ? row : (N - 1)) * F_IN;
    const _Float16* wrow = wt + (rc << 11);

    struct __attribute__((packed, aligned(4))) f4u { float f[4]; };

    f32x4 acc = {0.0f, 0.0f, 0.0f, 0.0f};
    int kb = g * 8;

    #pragma unroll 4
    for (int ch = 0; ch < 44; ++ch) {
        int k0 = ch * 32 + kb;
        f4u xa = *(const f4u*)&xr[k0];
        f4u xb = *(const f4u*)&xr[k0 + 4];
        f16x8 bv = *(const f16x8*)&wrow[k0];
        f16x8 av;
        #pragma unroll
        for (int j = 0; j < 4; ++j) {
            av[j]     = (_Float16)xa.f[j];
            av[j + 4] = (_Float16)xb.f[j];
        }
        acc = __builtin_amdgcn_mfma_f32_16x16x32_f16(av, bv, acc, 0, 0, 0);
    }
    {   // tail chunk, guarded
        int k0 = 1408 + kb;
        f16x8 av, bv;
        bv = *(const f16x8*)&wrow[k0];
        #pragma unroll
        for (int j = 0; j < 8; ++j) {
            int k = k0 + j;
            av[j] = (_Float16)((k < F_IN) ? xr[k] : 0.0f);
        }
        acc = __builtin_amdgcn_mfma_f32_16x16x32_f16(av, bv, acc, 0, 0, 0);
    }

    #pragma unroll
    for (int r = 0; r < 4; ++r) {           // C/D: col=lane&15, row=(lane>>4)*4+reg
        int grow = tile * 16 + g * 4 + r;
        if (grow < N) {
            float di = rsqrtf((float)cnt[grow] + 1.0f);
            s[grow * 16 + rc] = acc[r] * di;
        }
    }
}

// ------- aggA (rep'd, R12 structure) -------
__global__ __launch_bounds__(256) void k_aggA(
    const int* __restrict__ cnt, const int* __restrict__ bucket,
    const float* __restrict__ sin, const float* __restrict__ W,
    const float* __restrict__ bias, float* __restrict__ sout, int N, int rep, int zoff)
{
    __shared__ float w[256], bs[16];
    int tid = threadIdx.x;
    w[tid] = W[tid];
    if (tid < 16) bs[tid] = bias[tid];
    __syncthreads();

    int wave = tid >> 6, lane = tid & 63;
    int dst = blockIdx.x * 4 + wave;
    if (dst >= N) return;
    int g = lane >> 4, c = lane & 15;
    int deg = min(cnt[dst], BCAP);
    const int* bk = bucket + (size_t)dst * BCAP;

    int e0 = (lane < deg)      ? bk[lane]      : 0;
    int e1 = (64 + lane < deg) ? bk[64 + lane] : 0;

    for (int r = 0; r < rep; ++r) {
        int zo = r * zoff;
        float acc = (g == 0) ? sin[dst * 16 + c + zo] : 0.0f;
        for (int base = 0; base < deg; base += 32) {
            float vs = 0.0f;
            #pragma unroll
            for (int i = 0; i < 8; ++i) {
                int j = base + g + 4 * i;
                int sa = __shfl(e0, j & 63, 64), sb = __shfl(e1, j & 63, 64);
                int sv = (j < 64) ? sa : sb;
                float v = (j < deg) ? sin[sv * 16 + c + zo] : 0.0f;
                vs += v;
            }
            acc += vs;
        }
        acc += __shfl_xor(acc, 16, 64);
        acc += __shfl_xor(acc, 32, 64);

        float di = rsqrtf((float)cnt[dst] + 1.0f);
        float h = fmaxf(fmaf(di, acc, bs[c]), 0.0f);
        float t = 0.0f;
        #pragma unroll
        for (int k = 0; k < 16; ++k)
            t = fmaf(__shfl(h, k, 16), w[k * 16 + c], t);
        if (lane < 16) sout[dst * 16 + c] = di * t;
    }
}

// ------- aggB (rep'd) -------
__global__ __launch_bounds__(256) void k_aggB(
    const int* __restrict__ cnt, const int* __restrict__ bucket,
    const float* __restrict__ sin, const float* __restrict__ W,
    const float* __restrict__ bias, float* __restrict__ sout, int N, int rep, int zoff)
{
    __shared__ float w[112], bs[16];
    int tid = threadIdx.x;
    if (tid < 112) w[tid] = W[tid];
    if (tid < 16) bs[tid] = bias[tid];
    __syncthreads();

    int wave = tid >> 6, lane = tid & 63;
    int dst = blockIdx.x * 4 + wave;
    if (dst >= N) return;
    int g = lane >> 4, c = lane & 15;
    int deg = min(cnt[dst], BCAP);
    const int* bk = bucket + (size_t)dst * BCAP;

    int e0 = (lane < deg)      ? bk[lane]      : 0;
    int e1 = (64 + lane < deg) ? bk[64 + lane] : 0;

    for (int r = 0; r < rep; ++r) {
        int zo = r * zoff;
        float acc = (g == 0) ? sin[dst * 16 + c + zo] : 0.0f;
        for (int base = 0; base < deg; base += 32) {
            float vs = 0.0f;
            #pragma unroll
            for (int i = 0; i < 8; ++i) {
                int j = base + g + 4 * i;
                int sa = __shfl(e0, j & 63, 64), sb = __shfl(e1, j & 63, 64);
                int sv = (j < 64) ? sa : sb;
                float v = (j < deg) ? sin[sv * 16 + c + zo] : 0.0f;
                vs += v;
            }
            acc += vs;
        }
        acc += __shfl_xor(acc, 16, 64);
        acc += __shfl_xor(acc, 32, 64);

        float di = rsqrtf((float)cnt[dst] + 1.0f);
        float h = fmaxf(fmaf(di, acc, bs[c]), 0.0f);
        int cc = (c < 7) ? c : 0;
        float t = 0.0f;
        #pragma unroll
        for (int k = 0; k < 16; ++k)
            t = fmaf(__shfl(h, k, 16), w[k * 7 + cc], t);
        if (lane < 7) sout[dst * 7 + c] = di * t;
    }
}

// ------- aggC (rep'd) -------
__global__ __launch_bounds__(256) void k_aggC(
    const int* __restrict__ cnt, const int* __restrict__ bucket,
    const float* __restrict__ sin, const float* __restrict__ bias,
    float* __restrict__ out, int N, int rep, int zoff)
{
    __shared__ float bs[8];
    int tid = threadIdx.x;
    if (tid < 7) bs[tid] = bias[tid];
    if (tid == 7) bs[7] = 0.0f;
    __syncthreads();

    int wave = tid >> 6, lane = tid & 63;
    int dst = blockIdx.x * 4 + wave;
    if (dst >= N) return;
    int g8 = lane >> 3, c8 = lane & 7;
    bool c7 = (c8 < 7);
    int cc = c7 ? c8 : 0;
    int deg = min(cnt[dst], BCAP);
    const int* bk = bucket + (size_t)dst * BCAP;

    int e0 = (lane < deg)      ? bk[lane]      : 0;
    int e1 = (64 + lane < deg) ? bk[64 + lane] : 0;

    for (int r = 0; r < rep; ++r) {
        int zo = r * zoff;
        float acc = (g8 == 0 && c7) ? sin[dst * 7 + c8 + zo] : 0.0f;
        for (int base = 0; base < deg; base += 64) {
            float vs = 0.0f;
            #pragma unroll
            for (int i = 0; i < 8; ++i) {
                int j = base + g8 + 8 * i;
                int sa = __shfl(e0, j & 63, 64), sb = __shfl(e1, j & 63, 64);
                int sv = (j < 64) ? sa : sb;
                float v = (j < deg && c7) ? sin[sv * 7 + cc + zo] : 0.0f;
                vs += v;
            }
            acc += vs;
        }
        acc += __shfl_xor(acc, 8, 64);
        acc += __shfl_xor(acc, 16, 64);
        acc += __shfl_xor(acc, 32, 64);

        if (lane < 8) {
            float di = rsqrtf((float)cnt[dst] + 1.0f);
            float logit = c7 ? fmaf(di, acc, bs[c8]) : -1e30f;
            float m = logit;
            m = fmaxf(m, __shfl_xor(m, 1, 8));
            m = fmaxf(m, __shfl_xor(m, 2, 8));
            m = fmaxf(m, __shfl_xor(m, 4, 8));
            float e = c7 ? expf(logit - m) : 0.0f;
            float ssum = e;
            ssum += __shfl_xor(ssum, 1, 8);
            ssum += __shfl_xor(ssum, 2, 8);
            ssum += __shfl_xor(ssum, 4, 8);
            if (c7) out[dst * 7 + c8] = logit - m - logf(ssum);
        }
    }
}

extern "C" void kernel_launch(void* const* d_in, const int* in_sizes, int n_in,
                              void* d_out, int out_size, void* d_ws, size_t ws_size,
                              hipStream_t stream)
{
    const float* x  = (const float*)d_in[0];
    const float* W1 = (const float*)d_in[1];
    const float* b1 = (const float*)d_in[2];
    const float* W2 = (const float*)d_in[3];
    const float* b2 = (const float*)d_in[4];
    const float* W3 = (const float*)d_in[5];
    const float* b3 = (const float*)d_in[6];
    const int*   ei = (const int*)d_in[7];
    float* out = (float*)d_out;

    int N = in_sizes[0] / F_IN;
    int E = in_sizes[7] / 2;

    int*      cnt    = (int*)d_ws;                            // SREP*N
    int*      bucket = cnt + (size_t)SREP * N;                // SREP*N*BCAP
    _Float16* wt     = (_Float16*)(bucket + (size_t)SREP * N * BCAP); // 16*WSTR halfs
    float*    s1     = (float*)(wt + 16 * WSTR);              // 16N
    float*    s2     = s1 + 16 * (size_t)N;                   // 16N
    float*    s3     = s2 + 16 * (size_t)N;                   // 7N

    int nbP = (SREP * N + 255) / 256;
    int nbE = (E + 255) / 256;
    int nb4 = (N + 3) / 4;
    int ntiles = (N + 15) / 16;
    int nbG = (ntiles + 3) / 4;

    int zoff = 0;   // runtime zero: defeats cross-rep CSE

    k_prep   <<<nbP, 256, 0, stream>>>(W1, cnt, wt, N);
    k_scatter<<<nbE, 256, 0, stream>>>(ei, cnt, bucket, E, N, SREP);
    k_gemm   <<<nbG, 256, 0, stream>>>(x, wt, cnt, s1, N);
    k_aggA   <<<nb4, 256, 0, stream>>>(cnt, bucket, s1, W2, b1, s2, N, 8, zoff);
    k_aggB   <<<nb4, 256, 0, stream>>>(cnt, bucket, s2, W3, b2, s3, N, 9, zoff);
    k_aggC   <<<nb4, 256, 0, stream>>>(cnt, bucket, s3, b3, out, N, 13, zoff);
}